// Round 4
// baseline (6344.328 us; speedup 1.0000x reference)
//
#include <hip/hip_runtime.h>
#include <hip/hip_bf16.h>

typedef short bf16x8 __attribute__((ext_vector_type(8)));
typedef float f32x4 __attribute__((ext_vector_type(4)));

__device__ __forceinline__ unsigned short f2bf(float f) {
  union { float f; unsigned u; } c; c.f = f;
  unsigned u = c.u;
  return (unsigned short)((u + 0x7fffu + ((u >> 16) & 1u)) >> 16);
}
__device__ __forceinline__ float bf2f(unsigned short h) {
  union { unsigned u; float f; } c; c.u = ((unsigned)h) << 16;
  return c.f;
}

#define GL_LDS16(gp, lp)                                                        \
  __builtin_amdgcn_global_load_lds(                                             \
      (const __attribute__((address_space(1))) void*)(const void*)(gp),         \
      (__attribute__((address_space(3))) void*)(void*)(lp), 16, 0, 0)

// ---------------------------------------------------------------------------
// C[m,n] = sum_k A[m,k] * B[n,k]  (+ bias[n]), B^T layout. 128x128 tile,
// BK=32, 4 waves, 16x16x32 bf16 MFMA.
// OUT==0: fp32 C[row*ldc+col]   OUT==1: bf16 C[row*ldc+col]
// OUT==3: bf16 scatter  C[(col%768)*12288 + (col/768)*1024 + row]  (Vtilde^T)
//
// Occupancy-first pipeline: 2-deep LDS double buffer (32 KiB -> 5 blocks/CU,
// 20 waves/CU), 2 barriers/K-tile, counted vmcnt(4) (tile kt waited, tile
// kt+1 in flight). Race proof: reads of buf[kt&1] are fenced by
// lgkmcnt(0)+barrier2 BEFORE any wave issues stage(kt+2) into that buffer;
// stage(kt+1)'s landing is ordered by vmcnt(4)+barrier1 of iter kt+1.
// ---------------------------------------------------------------------------
template <int OUT>
__global__ __launch_bounds__(256, 5)
void gemm_bt(const unsigned short* __restrict__ A, int lda, long sAz,
             const unsigned short* __restrict__ B, int ldb, long sBz,
             void* __restrict__ Cout, int ldc, long sCz,
             const float* __restrict__ bias, int K)
{
  __shared__ unsigned short lds[2 * 256 * 32];   // 2 bufs x (128 A + 128 B rows) x 32

  const int tid  = threadIdx.x;
  const int lane = tid & 63;
  const int wave = tid >> 6;
  const int wn = wave & 1, wm = wave >> 1;
  const int m0 = blockIdx.y * 128;
  const int n0 = blockIdx.x * 128;
  A += (long)blockIdx.z * sAz;
  B += (long)blockIdx.z * sBz;

  // staging: slot = tid + s*256, row = slot>>2, phys chunk = tid&3; source
  // holds logical chunk (tid&3)^swz(row) (swz invariant across the 4 slots).
  const int srow = tid >> 2;
  const int swzs = (srow & 3) ^ ((srow >> 2) & 3);
  const int lc   = ((tid & 3) ^ swzs) * 8;
  const long ldaL = lda, ldbL = ldb;
  const unsigned short* gA0 = A + (long)(m0 + srow) * ldaL + lc;
  const unsigned short* gA1 = A + (long)(m0 + srow + 64) * ldaL + lc;
  const unsigned short* gB0 = B + (long)(n0 + srow) * ldbL + lc;
  const unsigned short* gB1 = B + (long)(n0 + srow + 64) * ldbL + lc;

  auto stage = [&](int kt) {
    unsigned short* lb = &lds[(kt & 1) * (256 * 32)];
    const long k0 = (long)kt * 32;
    GL_LDS16(gA0 + k0, &lb[(tid + 0 * 256) * 8]);
    GL_LDS16(gA1 + k0, &lb[(tid + 1 * 256) * 8]);
    GL_LDS16(gB0 + k0, &lb[(tid + 2 * 256) * 8]);
    GL_LDS16(gB1 + k0, &lb[(tid + 3 * 256) * 8]);
  };

  // fragment reads: row = base + m*16 + fr (bases multiple of 16)
  const int fr   = lane & 15;
  const int fkx  = lane >> 4;
  const int swzr = (fr & 3) ^ ((fr >> 2) & 3);
  const int pc   = (fkx ^ swzr) * 8;
  const int aRowBase = wm * 64;
  const int bRowBase = 128 + wn * 64;

  f32x4 acc[4][4] = {};
  const int nk = K >> 5;

  stage(0);
  stage(1);

  for (int kt = 0; kt < nk; ++kt) {
    if (kt + 1 < nk) asm volatile("s_waitcnt vmcnt(4)" ::: "memory");
    else             asm volatile("s_waitcnt vmcnt(0)" ::: "memory");
    __builtin_amdgcn_sched_barrier(0);
    __builtin_amdgcn_s_barrier();          // barrier1: tile kt visible to all
    __builtin_amdgcn_sched_barrier(0);

    const unsigned short* lb = &lds[(kt & 1) * (256 * 32)];
    bf16x8 af[4], bfr[4];
#pragma unroll
    for (int m = 0; m < 4; ++m)
      af[m] = *(const bf16x8*)&lb[(aRowBase + m * 16 + fr) * 32 + pc];
#pragma unroll
    for (int n = 0; n < 4; ++n)
      bfr[n] = *(const bf16x8*)&lb[(bRowBase + n * 16 + fr) * 32 + pc];

    asm volatile("s_waitcnt lgkmcnt(0)" ::: "memory");
    __builtin_amdgcn_sched_barrier(0);
    __builtin_amdgcn_s_barrier();          // barrier2: all reads of buf done
    __builtin_amdgcn_sched_barrier(0);
    if (kt + 2 < nk) stage(kt + 2);        // overwrite just-freed buffer

    __builtin_amdgcn_s_setprio(1);
#pragma unroll
    for (int m = 0; m < 4; ++m)
#pragma unroll
      for (int n = 0; n < 4; ++n)
        acc[m][n] = __builtin_amdgcn_mfma_f32_16x16x32_bf16(af[m], bfr[n],
                                                            acc[m][n], 0, 0, 0);
    __builtin_amdgcn_s_setprio(0);
  }

  // epilogue: C/D layout col = lane&15, row = (lane>>4)*4 + i  [m89/m91]
  const int crow = (lane >> 4) * 4;
  const int ccol = lane & 15;
#pragma unroll
  for (int n = 0; n < 4; ++n) {
    const int col = n0 + wn * 64 + n * 16 + ccol;
    const float bb = bias ? bias[col] : 0.0f;
#pragma unroll
    for (int m = 0; m < 4; ++m) {
      const int rowb = m0 + wm * 64 + m * 16 + crow;
      if (OUT == 0) {
        float* C = (float*)Cout + blockIdx.z * sCz;
#pragma unroll
        for (int i = 0; i < 4; ++i)
          C[(long)(rowb + i) * ldc + col] = acc[m][n][i] + bb;
      } else if (OUT == 1) {
        unsigned short* C = (unsigned short*)Cout + blockIdx.z * sCz;
#pragma unroll
        for (int i = 0; i < 4; ++i)
          C[(long)(rowb + i) * ldc + col] = f2bf(acc[m][n][i] + bb);
      } else {  // OUT==3: Vtilde^T[o][(h,t)]: col=(h*768+o), row=t
        unsigned short* C = (unsigned short*)Cout;
        const int hh = col / 768;
        const int oo = col - hh * 768;
        ushort4 pk;
        pk.x = f2bf(acc[m][n][0] + bb);
        pk.y = f2bf(acc[m][n][1] + bb);
        pk.z = f2bf(acc[m][n][2] + bb);
        pk.w = f2bf(acc[m][n][3] + bb);
        *(ushort4*)&C[(long)oo * 12288 + hh * 1024 + rowb] = pk;
      }
    }
  }
}

// ---------------------------------------------------------------------------
// In-place row softmax over bf16 segments of length 1024, with logit scale.
// ---------------------------------------------------------------------------
__global__ __launch_bounds__(256)
void softmax_rows(unsigned short* __restrict__ S, float inv_scale)
{
  __shared__ float red[8];
  unsigned short* p = S + (long)blockIdx.x * 1024 + threadIdx.x * 4;
  ushort4 raw = *(const ushort4*)p;
  float v0 = bf2f(raw.x) * inv_scale;
  float v1 = bf2f(raw.y) * inv_scale;
  float v2 = bf2f(raw.z) * inv_scale;
  float v3 = bf2f(raw.w) * inv_scale;

  float mx = fmaxf(fmaxf(v0, v1), fmaxf(v2, v3));
#pragma unroll
  for (int o = 32; o >= 1; o >>= 1) mx = fmaxf(mx, __shfl_xor(mx, o));
  const int w = threadIdx.x >> 6;
  if ((threadIdx.x & 63) == 0) red[w] = mx;
  __syncthreads();
  mx = fmaxf(fmaxf(red[0], red[1]), fmaxf(red[2], red[3]));

  float e0 = __expf(v0 - mx), e1 = __expf(v1 - mx);
  float e2 = __expf(v2 - mx), e3 = __expf(v3 - mx);
  float s = (e0 + e1) + (e2 + e3);
#pragma unroll
  for (int o = 32; o >= 1; o >>= 1) s += __shfl_xor(s, o);
  if ((threadIdx.x & 63) == 0) red[4 + w] = s;
  __syncthreads();
  s = (red[4] + red[5]) + (red[6] + red[7]);
  const float inv = 1.0f / s;

  ushort4 o4;
  o4.x = f2bf(e0 * inv); o4.y = f2bf(e1 * inv);
  o4.z = f2bf(e2 * inv); o4.w = f2bf(e3 * inv);
  *(ushort4*)p = o4;
}

// ---------------------------------------------------------------------------
__global__ __launch_bounds__(256)
void cast_f32_bf16(const float* __restrict__ src, unsigned short* __restrict__ dst,
                   int n)
{
  int i = (blockIdx.x * 256 + threadIdx.x) * 4;
  const int stride = gridDim.x * 256 * 4;
  for (; i < n; i += stride) {
    float4 f = *(const float4*)(src + i);
    ushort4 o;
    o.x = f2bf(f.x); o.y = f2bf(f.y); o.z = f2bf(f.z); o.w = f2bf(f.w);
    *(ushort4*)(dst + i) = o;
  }
}

// WvT[h][d][e] = Wv[h][e][d], f32 -> bf16.  grid (24,24,12), block 256 (32x8).
__global__ __launch_bounds__(256)
void transpose_cast_wv(const float* __restrict__ Wv, unsigned short* __restrict__ WvT)
{
  __shared__ unsigned short t[32][33];
  const int h = blockIdx.z;
  const int e0 = blockIdx.y * 32, d0 = blockIdx.x * 32;
  const int tx = threadIdx.x & 31, ty = threadIdx.x >> 5;
  const float* src = Wv + (long)h * 589824;
#pragma unroll
  for (int k = 0; k < 4; ++k)
    t[ty + 8 * k][tx] = f2bf(src[(long)(e0 + ty + 8 * k) * 768 + d0 + tx]);
  __syncthreads();
  unsigned short* dst = WvT + (long)h * 589824;
#pragma unroll
  for (int k = 0; k < 4; ++k)
    dst[(long)(d0 + ty + 8 * k) * 768 + e0 + tx] = t[tx][ty + 8 * k];
}

// bvo[h*768+o] = sum_e Wo[o][h*768+e] * bv[h*768+e].  One wave per output row.
__global__ __launch_bounds__(256)
void compute_bvo(const float* __restrict__ Wo, const float* __restrict__ bv,
                 float* __restrict__ bvo)
{
  const int r = blockIdx.x * 4 + (threadIdx.x >> 6);
  const int lane = threadIdx.x & 63;
  const int h = r / 768, o = r - h * 768;
  const float* wrow = Wo + (long)o * 9216 + h * 768;
  const float* brow = bv + h * 768;
  float acc = 0.f;
  for (int e = lane; e < 768; e += 64) acc += wrow[e] * brow[e];
#pragma unroll
  for (int off = 32; off >= 1; off >>= 1) acc += __shfl_xor(acc, off);
  if (lane == 0) bvo[r] = acc;
}

// out[i] = sum of 6 split-K partials + bias[col]
__global__ __launch_bounds__(256)
void reduce6_bias(const float* __restrict__ p, const float* __restrict__ bo,
                  float* __restrict__ out, int n, long sz)
{
  int i = (blockIdx.x * 256 + threadIdx.x) * 4;
  if (i >= n) return;
  float4 s = *(const float4*)(p + i);
#pragma unroll
  for (int z = 1; z < 6; ++z) {
    float4 q = *(const float4*)(p + z * sz + i);
    s.x += q.x; s.y += q.y; s.z += q.z; s.w += q.w;
  }
  const int col = i % 768;
  float4 bb = *(const float4*)(bo + col);
  s.x += bb.x; s.y += bb.y; s.z += bb.z; s.w += bb.w;
  *(float4*)(out + i) = s;
}

// ---------------------------------------------------------------------------
extern "C" void kernel_launch(void* const* d_in, const int* in_sizes, int n_in,
                              void* d_out, int out_size, void* d_ws, size_t ws_size,
                              hipStream_t stream)
{
  const float* X  = (const float*)d_in[0];
  const float* Wq = (const float*)d_in[1];
  const float* bq = (const float*)d_in[2];
  const float* Wk = (const float*)d_in[3];
  const float* bk = (const float*)d_in[4];
  const float* Wv = (const float*)d_in[5];
  const float* bv = (const float*)d_in[6];
  const float* Wo = (const float*)d_in[7];
  const float* bo = (const float*)d_in[8];

  // B=8, S=1024, D=768, H=12.  Fused algebra:
  //   Wvo_h = Wo_h @ Wv_h  (one-time);  bvo_h = Wo_h @ bv_h
  //   Vt_h  = X @ Wvo_h^T + bvo_h      (per batch, like a V-projection)
  //   out   = sum_h P_h @ Vt_h + bo    (softmax rows sum to 1 -> bvo exact)
  // Workspace (~118 MB): Xb 12.6 | Wb(q|k) 28.3 | Wvo 14.2 | bqk/bvo |
  //   qkreg 37.75 (time-shared: init WvT+Wob / qk / vT2+part) | P 25.2
  char* ws = (char*)d_ws;
  auto alloc = [&](long bytes) {
    char* p = ws;
    ws += (bytes + 255) & ~255l;
    return p;
  };
  unsigned short* Xb    = (unsigned short*)alloc(6291456l * 2);
  unsigned short* Wb    = (unsigned short*)alloc(14155776l * 2);   // Wq|Wk
  unsigned short* Wvo   = (unsigned short*)alloc(7077888l * 2);    // [(h,o)][d]
  float*          bqk   = (float*)alloc(18432l * 4);
  float*          bvo   = (float*)alloc(9216l * 4);
  char*           qkreg = alloc(37748736l);
  unsigned short* P     = (unsigned short*)alloc(12582912l * 2);   // [s][(h,t)]

  unsigned short* WvT  = (unsigned short*)qkreg;                   // init only
  unsigned short* Wob  = (unsigned short*)qkreg + 7077888;         // init only
  unsigned short* qk   = (unsigned short*)qkreg;                   // [1024][18432]
  unsigned short* vT2  = (unsigned short*)qkreg;                   // [768][12288]
  float*          part = (float*)(qkreg + 18874368);               // [6][1024][768]

  // ---- one-time init ----
  cast_f32_bf16<<<1024, 256, 0, stream>>>(X,  Xb, 6291456);
  cast_f32_bf16<<<1024, 256, 0, stream>>>(Wq, Wb,           7077888);
  cast_f32_bf16<<<1024, 256, 0, stream>>>(Wk, Wb + 7077888, 7077888);
  cast_f32_bf16<<<1024, 256, 0, stream>>>(Wo, Wob, 7077888);
  transpose_cast_wv<<<dim3(24, 24, 12), 256, 0, stream>>>(Wv, WvT);
  compute_bvo<<<2304, 256, 0, stream>>>(Wo, bv, bvo);
  hipMemcpyAsync(bqk,        bq, 9216 * 4, hipMemcpyDeviceToDevice, stream);
  hipMemcpyAsync(bqk + 9216, bk, 9216 * 4, hipMemcpyDeviceToDevice, stream);
  // Wvo[(h,o)][d] = sum_e Wo[o][h*768+e] * Wv[h][e][d]
  gemm_bt<1><<<dim3(6, 6, 12), 256, 0, stream>>>(
      Wob, 9216, 768, WvT, 768, 589824, Wvo, 768, 589824, nullptr, 768);

  for (int b = 0; b < 8; ++b) {
    const unsigned short* Xbb = Xb + (long)b * 786432;

    // 1) Q,K projection -> qk [1024][18432]
    gemm_bt<1><<<dim3(144, 8, 1), 256, 0, stream>>>(
        Xbb, 768, 0, Wb, 768, 0, qk, 18432, 0, bqk, 768);

    // 2) scores: P[s][h*1024+t] = q_h[s,:] . k_h[t,:]   (z = head)
    gemm_bt<1><<<dim3(8, 8, 12), 256, 0, stream>>>(
        qk, 18432, 768, qk + 9216, 18432, 768, P, 12288, 1024, nullptr, 768);

    // 3) softmax over t (scale 1/768^2), in place; qk now dead
    softmax_rows<<<12288, 256, 0, stream>>>(P, 1.0f / 589824.0f);

    // 4) Vtilde-projection, scatter-transposed: vT2[o][(h,t)]
    gemm_bt<3><<<dim3(72, 8, 1), 256, 0, stream>>>(
        Xbb, 768, 0, Wvo, 768, 0, vT2, 12288, 0, bvo, 768);

    // 5) PV': part[z][s][o] = sum_{k in z-chunk} P[s][k] * vT2[o][k]
    gemm_bt<0><<<dim3(6, 8, 6), 256, 0, stream>>>(
        P, 12288, 2048, vT2, 12288, 2048, part, 768, 786432, nullptr, 2048);

    // 6) out[b*1024+s][o] = sum_z part + bo
    reduce6_bias<<<768, 256, 0, stream>>>(
        part, bo, (float*)d_out + (long)b * 786432, 786432, 786432);
  }

  (void)in_sizes; (void)n_in; (void)out_size; (void)ws_size;
}

// Round 5
// 1439.157 us; speedup vs baseline: 4.4084x; 4.4084x over previous
//
#include <hip/hip_runtime.h>
#include <hip/hip_bf16.h>

typedef short bf16x8 __attribute__((ext_vector_type(8)));
typedef float f32x4 __attribute__((ext_vector_type(4)));

__device__ __forceinline__ unsigned short f2bf(float f) {
  union { float f; unsigned u; } c; c.f = f;
  unsigned u = c.u;
  return (unsigned short)((u + 0x7fffu + ((u >> 16) & 1u)) >> 16);
}
__device__ __forceinline__ float bf2f(unsigned short h) {
  union { unsigned u; float f; } c; c.u = ((unsigned)h) << 16;
  return c.f;
}

#define GL_LDS16(gp, lp)                                                        \
  __builtin_amdgcn_global_load_lds(                                             \
      (const __attribute__((address_space(1))) void*)(const void*)(gp),         \
      (__attribute__((address_space(3))) void*)(void*)(lp), 16, 0, 0)

// ---------------------------------------------------------------------------
// C[m,n] = sum_k A[m,k] * B[n,k]  (+ bias[n]), B^T layout. 128x128 tile,
// BK=32, 4 waves, 16x16x32 bf16 MFMA.
// OUT==0: fp32 C[row*ldc+col]   OUT==1: bf16 C[row*ldc+col]
// OUT==3: bf16 scatter  C[(col%768)*12288 + (col/768)*1024 + row]  (Vtilde^T)
//
// 2-deep LDS double buffer (32 KiB), 2 barriers/K-tile, counted vmcnt(4).
// NO min-waves clamp: round-4's __launch_bounds__(256,5) forced VGPR=48 and
// spilled acc[4][4] to scratch (807 MB writes/dispatch). Compiler-chosen
// ~88 VGPR -> 4 waves/SIMD (16 waves/CU), LDS limit 5 blocks -> VGPR-bound 4.
// Race proof: reads of buf[kt&1] are fenced by lgkmcnt(0)+barrier2 BEFORE any
// wave issues stage(kt+2) into that buffer; stage(kt)'s landing is ordered by
// vmcnt(4) (FIFO drain) + barrier1.
// ---------------------------------------------------------------------------
template <int OUT>
__global__ __launch_bounds__(256)
void gemm_bt(const unsigned short* __restrict__ A, int lda, long sAz,
             const unsigned short* __restrict__ B, int ldb, long sBz,
             void* __restrict__ Cout, int ldc, long sCz,
             const float* __restrict__ bias, int K)
{
  __shared__ unsigned short lds[2 * 256 * 32];   // 2 bufs x (128 A + 128 B rows) x 32

  const int tid  = threadIdx.x;
  const int lane = tid & 63;
  const int wave = tid >> 6;
  const int wn = wave & 1, wm = wave >> 1;
  const int m0 = blockIdx.y * 128;
  const int n0 = blockIdx.x * 128;
  A += (long)blockIdx.z * sAz;
  B += (long)blockIdx.z * sBz;

  // staging: slot = tid + s*256, row = slot>>2, phys chunk = tid&3; source
  // holds logical chunk (tid&3)^swz(row) (swz invariant across the 4 slots).
  const int srow = tid >> 2;
  const int swzs = (srow & 3) ^ ((srow >> 2) & 3);
  const int lc   = ((tid & 3) ^ swzs) * 8;
  const long ldaL = lda, ldbL = ldb;
  const unsigned short* gA0 = A + (long)(m0 + srow) * ldaL + lc;
  const unsigned short* gA1 = A + (long)(m0 + srow + 64) * ldaL + lc;
  const unsigned short* gB0 = B + (long)(n0 + srow) * ldbL + lc;
  const unsigned short* gB1 = B + (long)(n0 + srow + 64) * ldbL + lc;

  auto stage = [&](int kt) {
    unsigned short* lb = &lds[(kt & 1) * (256 * 32)];
    const long k0 = (long)kt * 32;
    GL_LDS16(gA0 + k0, &lb[(tid + 0 * 256) * 8]);
    GL_LDS16(gA1 + k0, &lb[(tid + 1 * 256) * 8]);
    GL_LDS16(gB0 + k0, &lb[(tid + 2 * 256) * 8]);
    GL_LDS16(gB1 + k0, &lb[(tid + 3 * 256) * 8]);
  };

  // fragment reads: row = base + m*16 + fr (bases multiple of 16)
  const int fr   = lane & 15;
  const int fkx  = lane >> 4;
  const int swzr = (fr & 3) ^ ((fr >> 2) & 3);
  const int pc   = (fkx ^ swzr) * 8;
  const int aRowBase = wm * 64;
  const int bRowBase = 128 + wn * 64;

  f32x4 acc[4][4] = {};
  const int nk = K >> 5;

  stage(0);
  stage(1);

  for (int kt = 0; kt < nk; ++kt) {
    if (kt + 1 < nk) asm volatile("s_waitcnt vmcnt(4)" ::: "memory");
    else             asm volatile("s_waitcnt vmcnt(0)" ::: "memory");
    __builtin_amdgcn_sched_barrier(0);
    __builtin_amdgcn_s_barrier();          // barrier1: tile kt visible to all
    __builtin_amdgcn_sched_barrier(0);

    const unsigned short* lb = &lds[(kt & 1) * (256 * 32)];
    bf16x8 af[4], bfr[4];
#pragma unroll
    for (int m = 0; m < 4; ++m)
      af[m] = *(const bf16x8*)&lb[(aRowBase + m * 16 + fr) * 32 + pc];
#pragma unroll
    for (int n = 0; n < 4; ++n)
      bfr[n] = *(const bf16x8*)&lb[(bRowBase + n * 16 + fr) * 32 + pc];

    asm volatile("s_waitcnt lgkmcnt(0)" ::: "memory");
    __builtin_amdgcn_sched_barrier(0);
    __builtin_amdgcn_s_barrier();          // barrier2: all reads of buf done
    __builtin_amdgcn_sched_barrier(0);
    if (kt + 2 < nk) stage(kt + 2);        // overwrite just-freed buffer

    __builtin_amdgcn_s_setprio(1);
#pragma unroll
    for (int m = 0; m < 4; ++m)
#pragma unroll
      for (int n = 0; n < 4; ++n)
        acc[m][n] = __builtin_amdgcn_mfma_f32_16x16x32_bf16(af[m], bfr[n],
                                                            acc[m][n], 0, 0, 0);
    __builtin_amdgcn_s_setprio(0);
  }

  // epilogue: C/D layout col = lane&15, row = (lane>>4)*4 + i  [m89/m91]
  const int crow = (lane >> 4) * 4;
  const int ccol = lane & 15;
#pragma unroll
  for (int n = 0; n < 4; ++n) {
    const int col = n0 + wn * 64 + n * 16 + ccol;
    const float bb = bias ? bias[col] : 0.0f;
#pragma unroll
    for (int m = 0; m < 4; ++m) {
      const int rowb = m0 + wm * 64 + m * 16 + crow;
      if (OUT == 0) {
        float* C = (float*)Cout + blockIdx.z * sCz;
#pragma unroll
        for (int i = 0; i < 4; ++i)
          C[(long)(rowb + i) * ldc + col] = acc[m][n][i] + bb;
      } else if (OUT == 1) {
        unsigned short* C = (unsigned short*)Cout + blockIdx.z * sCz;
#pragma unroll
        for (int i = 0; i < 4; ++i)
          C[(long)(rowb + i) * ldc + col] = f2bf(acc[m][n][i] + bb);
      } else {  // OUT==3: Vtilde^T[o][(h,t)]: col=(h*768+o), row=t
        unsigned short* C = (unsigned short*)Cout;
        const int hh = col / 768;
        const int oo = col - hh * 768;
        ushort4 pk;
        pk.x = f2bf(acc[m][n][0] + bb);
        pk.y = f2bf(acc[m][n][1] + bb);
        pk.z = f2bf(acc[m][n][2] + bb);
        pk.w = f2bf(acc[m][n][3] + bb);
        *(ushort4*)&C[(long)oo * 12288 + hh * 1024 + rowb] = pk;
      }
    }
  }
}

// ---------------------------------------------------------------------------
// In-place row softmax over bf16 segments of length 1024, with logit scale.
// ---------------------------------------------------------------------------
__global__ __launch_bounds__(256)
void softmax_rows(unsigned short* __restrict__ S, float inv_scale)
{
  __shared__ float red[8];
  unsigned short* p = S + (long)blockIdx.x * 1024 + threadIdx.x * 4;
  ushort4 raw = *(const ushort4*)p;
  float v0 = bf2f(raw.x) * inv_scale;
  float v1 = bf2f(raw.y) * inv_scale;
  float v2 = bf2f(raw.z) * inv_scale;
  float v3 = bf2f(raw.w) * inv_scale;

  float mx = fmaxf(fmaxf(v0, v1), fmaxf(v2, v3));
#pragma unroll
  for (int o = 32; o >= 1; o >>= 1) mx = fmaxf(mx, __shfl_xor(mx, o));
  const int w = threadIdx.x >> 6;
  if ((threadIdx.x & 63) == 0) red[w] = mx;
  __syncthreads();
  mx = fmaxf(fmaxf(red[0], red[1]), fmaxf(red[2], red[3]));

  float e0 = __expf(v0 - mx), e1 = __expf(v1 - mx);
  float e2 = __expf(v2 - mx), e3 = __expf(v3 - mx);
  float s = (e0 + e1) + (e2 + e3);
#pragma unroll
  for (int o = 32; o >= 1; o >>= 1) s += __shfl_xor(s, o);
  if ((threadIdx.x & 63) == 0) red[4 + w] = s;
  __syncthreads();
  s = (red[4] + red[5]) + (red[6] + red[7]);
  const float inv = 1.0f / s;

  ushort4 o4;
  o4.x = f2bf(e0 * inv); o4.y = f2bf(e1 * inv);
  o4.z = f2bf(e2 * inv); o4.w = f2bf(e3 * inv);
  *(ushort4*)p = o4;
}

// ---------------------------------------------------------------------------
__global__ __launch_bounds__(256)
void cast_f32_bf16(const float* __restrict__ src, unsigned short* __restrict__ dst,
                   int n)
{
  int i = (blockIdx.x * 256 + threadIdx.x) * 4;
  const int stride = gridDim.x * 256 * 4;
  for (; i < n; i += stride) {
    float4 f = *(const float4*)(src + i);
    ushort4 o;
    o.x = f2bf(f.x); o.y = f2bf(f.y); o.z = f2bf(f.z); o.w = f2bf(f.w);
    *(ushort4*)(dst + i) = o;
  }
}

// WvT[h][d][e] = Wv[h][e][d], f32 -> bf16.  grid (24,24,12), block 256 (32x8).
__global__ __launch_bounds__(256)
void transpose_cast_wv(const float* __restrict__ Wv, unsigned short* __restrict__ WvT)
{
  __shared__ unsigned short t[32][33];
  const int h = blockIdx.z;
  const int e0 = blockIdx.y * 32, d0 = blockIdx.x * 32;
  const int tx = threadIdx.x & 31, ty = threadIdx.x >> 5;
  const float* src = Wv + (long)h * 589824;
#pragma unroll
  for (int k = 0; k < 4; ++k)
    t[ty + 8 * k][tx] = f2bf(src[(long)(e0 + ty + 8 * k) * 768 + d0 + tx]);
  __syncthreads();
  unsigned short* dst = WvT + (long)h * 589824;
#pragma unroll
  for (int k = 0; k < 4; ++k)
    dst[(long)(d0 + ty + 8 * k) * 768 + e0 + tx] = t[tx][ty + 8 * k];
}

// bvo[h*768+o] = sum_e Wo[o][h*768+e] * bv[h*768+e].  One wave per output row.
__global__ __launch_bounds__(256)
void compute_bvo(const float* __restrict__ Wo, const float* __restrict__ bv,
                 float* __restrict__ bvo)
{
  const int r = blockIdx.x * 4 + (threadIdx.x >> 6);
  const int lane = threadIdx.x & 63;
  const int h = r / 768, o = r - h * 768;
  const float* wrow = Wo + (long)o * 9216 + h * 768;
  const float* brow = bv + h * 768;
  float acc = 0.f;
  for (int e = lane; e < 768; e += 64) acc += wrow[e] * brow[e];
#pragma unroll
  for (int off = 32; off >= 1; off >>= 1) acc += __shfl_xor(acc, off);
  if (lane == 0) bvo[r] = acc;
}

// out[i] = sum of 6 split-K partials + bias[col]
__global__ __launch_bounds__(256)
void reduce6_bias(const float* __restrict__ p, const float* __restrict__ bo,
                  float* __restrict__ out, int n, long sz)
{
  int i = (blockIdx.x * 256 + threadIdx.x) * 4;
  if (i >= n) return;
  float4 s = *(const float4*)(p + i);
#pragma unroll
  for (int z = 1; z < 6; ++z) {
    float4 q = *(const float4*)(p + z * sz + i);
    s.x += q.x; s.y += q.y; s.z += q.z; s.w += q.w;
  }
  const int col = i % 768;
  float4 bb = *(const float4*)(bo + col);
  s.x += bb.x; s.y += bb.y; s.z += bb.z; s.w += bb.w;
  *(float4*)(out + i) = s;
}

// ---------------------------------------------------------------------------
extern "C" void kernel_launch(void* const* d_in, const int* in_sizes, int n_in,
                              void* d_out, int out_size, void* d_ws, size_t ws_size,
                              hipStream_t stream)
{
  const float* X  = (const float*)d_in[0];
  const float* Wq = (const float*)d_in[1];
  const float* bq = (const float*)d_in[2];
  const float* Wk = (const float*)d_in[3];
  const float* bk = (const float*)d_in[4];
  const float* Wv = (const float*)d_in[5];
  const float* bv = (const float*)d_in[6];
  const float* Wo = (const float*)d_in[7];
  const float* bo = (const float*)d_in[8];

  // B=8, S=1024, D=768, H=12.  Fused algebra:
  //   Wvo_h = Wo_h @ Wv_h  (one-time);  bvo_h = Wo_h @ bv_h
  //   Vt_h  = X @ Wvo_h^T + bvo_h      (per batch)
  //   out   = sum_h P_h @ Vt_h + bo    (softmax rows sum to 1 -> bvo exact)
  char* ws = (char*)d_ws;
  auto alloc = [&](long bytes) {
    char* p = ws;
    ws += (bytes + 255) & ~255l;
    return p;
  };
  unsigned short* Xb    = (unsigned short*)alloc(6291456l * 2);
  unsigned short* Wb    = (unsigned short*)alloc(14155776l * 2);   // Wq|Wk
  unsigned short* Wvo   = (unsigned short*)alloc(7077888l * 2);    // [(h,o)][d]
  float*          bqk   = (float*)alloc(18432l * 4);
  float*          bvo   = (float*)alloc(9216l * 4);
  char*           qkreg = alloc(37748736l);
  unsigned short* P     = (unsigned short*)alloc(12582912l * 2);   // [s][(h,t)]

  unsigned short* WvT  = (unsigned short*)qkreg;                   // init only
  unsigned short* Wob  = (unsigned short*)qkreg + 7077888;         // init only
  unsigned short* qk   = (unsigned short*)qkreg;                   // [1024][18432]
  unsigned short* vT2  = (unsigned short*)qkreg;                   // [768][12288]
  float*          part = (float*)(qkreg + 18874368);               // [6][1024][768]

  // ---- one-time init ----
  cast_f32_bf16<<<1024, 256, 0, stream>>>(X,  Xb, 6291456);
  cast_f32_bf16<<<1024, 256, 0, stream>>>(Wq, Wb,           7077888);
  cast_f32_bf16<<<1024, 256, 0, stream>>>(Wk, Wb + 7077888, 7077888);
  cast_f32_bf16<<<1024, 256, 0, stream>>>(Wo, Wob, 7077888);
  transpose_cast_wv<<<dim3(24, 24, 12), 256, 0, stream>>>(Wv, WvT);
  compute_bvo<<<2304, 256, 0, stream>>>(Wo, bv, bvo);
  hipMemcpyAsync(bqk,        bq, 9216 * 4, hipMemcpyDeviceToDevice, stream);
  hipMemcpyAsync(bqk + 9216, bk, 9216 * 4, hipMemcpyDeviceToDevice, stream);
  // Wvo[(h,o)][d] = sum_e Wo[o][h*768+e] * Wv[h][e][d]
  gemm_bt<1><<<dim3(6, 6, 12), 256, 0, stream>>>(
      Wob, 9216, 768, WvT, 768, 589824, Wvo, 768, 589824, nullptr, 768);

  for (int b = 0; b < 8; ++b) {
    const unsigned short* Xbb = Xb + (long)b * 786432;

    // 1) Q,K projection -> qk [1024][18432]
    gemm_bt<1><<<dim3(144, 8, 1), 256, 0, stream>>>(
        Xbb, 768, 0, Wb, 768, 0, qk, 18432, 0, bqk, 768);

    // 2) scores: P[s][h*1024+t] = q_h[s,:] . k_h[t,:]   (z = head)
    gemm_bt<1><<<dim3(8, 8, 12), 256, 0, stream>>>(
        qk, 18432, 768, qk + 9216, 18432, 768, P, 12288, 1024, nullptr, 768);

    // 3) softmax over t (scale 1/768^2), in place; qk now dead
    softmax_rows<<<12288, 256, 0, stream>>>(P, 1.0f / 589824.0f);

    // 4) Vtilde-projection, scatter-transposed: vT2[o][(h,t)]
    gemm_bt<3><<<dim3(72, 8, 1), 256, 0, stream>>>(
        Xbb, 768, 0, Wvo, 768, 0, vT2, 12288, 0, bvo, 768);

    // 5) PV': part[z][s][o] = sum_{k in z-chunk} P[s][k] * vT2[o][k]
    gemm_bt<0><<<dim3(6, 8, 6), 256, 0, stream>>>(
        P, 12288, 2048, vT2, 12288, 2048, part, 768, 786432, nullptr, 2048);

    // 6) out[b*1024+s][o] = sum_z part + bo
    reduce6_bias<<<768, 256, 0, stream>>>(
        part, bo, (float*)d_out + (long)b * 786432, 786432, 786432);
  }

  (void)in_sizes; (void)n_in; (void)out_size; (void)ws_size;
}